// Round 14
// baseline (227.890 us; speedup 1.0000x reference)
//
#include <hip/hip_runtime.h>
#include <hip/hip_bf16.h>
#include <math.h>

constexpr int Bsz = 64, Cctx = 200, Hdim = 1024, Vv = 50257;
constexpr float NEG_INF_V = -100000.0f;

typedef __attribute__((ext_vector_type(8))) short s16x8;
typedef __attribute__((ext_vector_type(4))) float fx4;
typedef unsigned int u32;

__device__ __forceinline__ unsigned short f2bf(float f) {
  unsigned int u = __builtin_bit_cast(unsigned int, f);
  unsigned int r = (u + 0x7fffu + ((u >> 16) & 1u)) >> 16;
  return (unsigned short)r;
}

__device__ __forceinline__ float fast_tanh(float x) {
  float e2 = __expf(2.f * x);
  return 1.f - 2.f / (e2 + 1.f);
}

__device__ __forceinline__ void gl_lds16(const unsigned short* g, unsigned short* l) {
  __builtin_amdgcn_global_load_lds(
      (const __attribute__((address_space(1))) u32*)g,
      (__attribute__((address_space(3))) u32*)l, 16, 0, 0);
}

// ---------- attention GEMM: 512-thr 128x128 tile, 32KB LDS single-buf, XOR swizzle ----------
// 8 waves = 4M x 2N; ~3 blocks/CU resident -> ~24 waves/CU (round-13 level) at HALF the
// staged bytes (A+B staged 8x not 16x). N-split waves write SEPARATE partial slots (no race).
__global__ __launch_bounds__(512)
void gemm_att(const unsigned short* __restrict__ Ab, const unsigned short* __restrict__ Bb,
              const float* __restrict__ qmat, const float* __restrict__ vvec,
              float* __restrict__ part_sc) {
  __shared__ unsigned short As[128 * 64];   // 16 KB
  __shared__ unsigned short Bs[128 * 64];   // 16 KB
  int f = blockIdx.x + blockIdx.y * 8;      // grid (8,104)
  int xcd = f & 7, jj = f >> 3;
  int my = xcd + 8 * (jj % 13), mx = jj / 13;   // 13 M-panels per XCD share L2
  if (my >= 100) return;
  const int bm0 = my * 128, bn0 = mx * 128;
  const int tid = threadIdx.x, lane = tid & 63, wid = tid >> 6;
  const int wm0 = (wid >> 1) * 32;          // 4 M-wave rows x 32
  const int wnr = wid & 1;                  // 2 N-wave cols x 64
  const int wn0 = wnr * 64;
  const int ar = lane & 15, q4 = lane >> 4;
  const int sw = ar & 7;

  fx4 acc[2][4] = {};

  for (int t = 0; t < 16; ++t) {
    const int kt = t * 64;
    #pragma unroll
    for (int i = 0; i < 2; ++i) {           // A: 1024 16B-chunks / 512 thr
      int s = tid + i * 512;
      int row = s >> 3;
      int sc = ((s & 7) ^ (row & 7)) * 8;
      gl_lds16(&Ab[(size_t)(bm0 + row) * Hdim + kt + sc], &As[s * 8]);
    }
    #pragma unroll
    for (int i = 0; i < 2; ++i) {           // B: 1024 chunks
      int s = tid + i * 512;
      int row = s >> 3;
      int sc = ((s & 7) ^ (row & 7)) * 8;
      gl_lds16(&Bb[(size_t)(bn0 + row) * Hdim + kt + sc], &Bs[s * 8]);
    }
    __syncthreads();
    #pragma unroll
    for (int kk = 0; kk < 2; ++kk) {
      s16x8 a[2], b[4];
      #pragma unroll
      for (int i = 0; i < 2; ++i)
        a[i] = *reinterpret_cast<const s16x8*>(
            &As[(wm0 + i * 16 + ar) * 64 + (((kk * 4 + q4) ^ sw) * 8)]);
      #pragma unroll
      for (int j2 = 0; j2 < 4; ++j2)
        b[j2] = *reinterpret_cast<const s16x8*>(
            &Bs[(wn0 + j2 * 16 + ar) * 64 + (((kk * 4 + q4) ^ sw) * 8)]);
      #pragma unroll
      for (int i = 0; i < 2; ++i)
        #pragma unroll
        for (int j2 = 0; j2 < 4; ++j2)
          acc[i][j2] = __builtin_amdgcn_mfma_f32_16x16x32_bf16(a[i], b[j2], acc[i][j2], 0, 0, 0);
    }
    __syncthreads();
  }

  const int rg = q4 * 4, cg = ar;
  const int slot = mx * 2 + wnr;            // 16 partial slots; unique writer per (slot,row)
  #pragma unroll
  for (int i = 0; i < 2; ++i) {
    #pragma unroll
    for (int p = 0; p < 4; ++p) {
      int mg = bm0 + wm0 + i * 16 + rg + p;
      int brow = mg & 63;
      float rs = 0.f;
      #pragma unroll
      for (int j2 = 0; j2 < 4; ++j2) {
        int ng = bn0 + wn0 + j2 * 16 + cg;
        float t = fast_tanh(acc[i][j2][p] + qmat[brow * Hdim + ng]);
        rs += t * vvec[ng];
      }
      rs += __shfl_xor(rs, 1); rs += __shfl_xor(rs, 2);
      rs += __shfl_xor(rs, 4); rs += __shfl_xor(rs, 8);
      if (cg == 0) part_sc[slot * 12800 + brow * Cctx + (mg >> 6)] = rs;
    }
  }
}

// ---------- 1-wave streaming GEMM body, depth-1 prefetch ----------
__device__ __forceinline__ void stream_body(const unsigned short* ap, const float* bp,
                                            int stride, int extent, fx4 acc[4]) {
  float4 b0 = *reinterpret_cast<const float4*>(bp);
  float4 b1 = *reinterpret_cast<const float4*>(bp + 4);
  float4 b2 = *reinterpret_cast<const float4*>(bp + 32);
  float4 b3 = *reinterpret_cast<const float4*>(bp + 36);
  for (int kt = 0; kt < extent; kt += 64) {
    float4 c0 = b0, c1 = b1, c2 = b2, c3 = b3;
    if (kt + 64 < extent) {
      b0 = *reinterpret_cast<const float4*>(bp + kt + 64);
      b1 = *reinterpret_cast<const float4*>(bp + kt + 68);
      b2 = *reinterpret_cast<const float4*>(bp + kt + 96);
      b3 = *reinterpret_cast<const float4*>(bp + kt + 100);
    }
    s16x8 bf0, bf1;
    bf0[0] = (short)f2bf(c0.x); bf0[1] = (short)f2bf(c0.y);
    bf0[2] = (short)f2bf(c0.z); bf0[3] = (short)f2bf(c0.w);
    bf0[4] = (short)f2bf(c1.x); bf0[5] = (short)f2bf(c1.y);
    bf0[6] = (short)f2bf(c1.z); bf0[7] = (short)f2bf(c1.w);
    bf1[0] = (short)f2bf(c2.x); bf1[1] = (short)f2bf(c2.y);
    bf1[2] = (short)f2bf(c2.z); bf1[3] = (short)f2bf(c2.w);
    bf1[4] = (short)f2bf(c3.x); bf1[5] = (short)f2bf(c3.y);
    bf1[6] = (short)f2bf(c3.z); bf1[7] = (short)f2bf(c3.w);
    #pragma unroll
    for (int i = 0; i < 4; ++i) {
      s16x8 af = *reinterpret_cast<const s16x8*>(ap + (size_t)i * 16 * stride + kt);
      acc[i] = __builtin_amdgcn_mfma_f32_16x16x32_bf16(af, bf0, acc[i], 0, 0, 0);
    }
    #pragma unroll
    for (int i = 0; i < 4; ++i) {
      s16x8 af = *reinterpret_cast<const s16x8*>(ap + (size_t)i * 16 * stride + kt + 32);
      acc[i] = __builtin_amdgcn_mfma_f32_16x16x32_bf16(af, bf1, acc[i], 0, 0, 0);
    }
  }
}

template<int EPI>  // 0: plain, 2: +bias
__global__ __launch_bounds__(64)
void stream_gemm(const unsigned short* __restrict__ Ab,
                 const float* __restrict__ Bm, int N, int K,
                 const float* __restrict__ bias, float* __restrict__ Cout) {
  const int lane = threadIdx.x;
  const int n0 = blockIdx.x * 16;
  const int c = lane & 15, qq = lane >> 4;
  const int brow = min(n0 + c, N - 1);
  fx4 acc[4] = {};
  stream_body(Ab + (size_t)c * K + qq * 8, Bm + (size_t)brow * K + qq * 8, K, K, acc);
  const int n = n0 + c;
  if (n < N) {
    float bv = (EPI == 2) ? bias[n] : 0.f;
    #pragma unroll
    for (int i = 0; i < 4; ++i)
      #pragma unroll
      for (int p = 0; p < 4; ++p)
        Cout[(size_t)(i * 16 + qq * 4 + p) * N + n] = acc[i][p] + bv;
  }
}

__global__ __launch_bounds__(64)
void qgh_gemm(const unsigned short* __restrict__ h0b, const float* __restrict__ Wt,
              const float* __restrict__ Whh, const float* __restrict__ bhh,
              float* __restrict__ q, float* __restrict__ gh) {
  const int lane = threadIdx.x;
  const int gw = blockIdx.x;
  const bool isq = gw < 64;
  const int n0 = isq ? gw * 16 : (gw - 64) * 16;
  const int N = isq ? 1024 : 3072;
  const float* B = isq ? Wt : Whh;
  const int c = lane & 15, qq = lane >> 4;
  fx4 acc[4] = {};
  stream_body(h0b + (size_t)c * 1024 + qq * 8, B + (size_t)(n0 + c) * 1024 + qq * 8,
              1024, 1024, acc);
  const int n = n0 + c;
  float bv = isq ? 0.f : bhh[n];
  float* C = isq ? q : gh;
  #pragma unroll
  for (int i = 0; i < 4; ++i)
    #pragma unroll
    for (int p = 0; p < 4; ++p)
      C[(size_t)(i * 16 + qq * 4 + p) * N + n] = acc[i][p] + bv;
}

__global__ __launch_bounds__(64)
void gi_split(const unsigned short* __restrict__ xb, const float* __restrict__ Wih,
              float* __restrict__ part) {
  const int lane = threadIdx.x;
  const int t = blockIdx.x;
  const int w = blockIdx.y;
  const int c = lane & 15, qq = lane >> 4;
  constexpr int K = 3072, CH = 768;
  fx4 acc[4] = {};
  stream_body(xb + (size_t)c * K + w * CH + qq * 8,
              Wih + (size_t)(t * 16 + c) * K + w * CH + qq * 8, K, CH, acc);
  float* po = part + (size_t)w * 64 * 3072;
  const int n = t * 16 + c;
  #pragma unroll
  for (int i = 0; i < 4; ++i)
    #pragma unroll
    for (int p = 0; p < 4; ++p)
      po[(size_t)(i * 16 + qq * 4 + p) * 3072 + n] = acc[i][p];
}

// ---------- prep: W transpose (f32), U transpose (bf16), h0 conv ----------
__global__ __launch_bounds__(256)
void prep(const float* __restrict__ dW, const float* __restrict__ dU,
          const float* __restrict__ h0, float* __restrict__ Wt,
          unsigned short* __restrict__ ub, unsigned short* __restrict__ h0b) {
  const int z = blockIdx.z;
  const int tx = threadIdx.x & 31, ty = threadIdx.x >> 5;
  if (z < 2) {
    __shared__ float t[32][33];
    const float* in = z ? dU : dW;
    int bx = blockIdx.x * 32, by = blockIdx.y * 32;
    #pragma unroll
    for (int r = 0; r < 32; r += 8) t[ty + r][tx] = in[(size_t)(by + ty + r) * 1024 + bx + tx];
    __syncthreads();
    if (z == 0) {
      #pragma unroll
      for (int r = 0; r < 32; r += 8) Wt[(size_t)(bx + ty + r) * 1024 + by + tx] = t[tx][ty + r];
    } else {
      #pragma unroll
      for (int r = 0; r < 32; r += 8) ub[(size_t)(bx + ty + r) * 1024 + by + tx] = f2bf(t[tx][ty + r]);
    }
  } else {
    if (blockIdx.y) return;
    size_t i = (size_t)(blockIdx.x * 256 + threadIdx.x) * 8;
    float4 a = *reinterpret_cast<const float4*>(h0 + i);
    float4 b = *reinterpret_cast<const float4*>(h0 + i + 4);
    s16x8 h;
    h[0] = (short)f2bf(a.x); h[1] = (short)f2bf(a.y); h[2] = (short)f2bf(a.z); h[3] = (short)f2bf(a.w);
    h[4] = (short)f2bf(b.x); h[5] = (short)f2bf(b.y); h[6] = (short)f2bf(b.z); h[7] = (short)f2bf(b.w);
    *reinterpret_cast<s16x8*>(h0b + i) = h;
  }
}

__global__ void conv_bf16(const float* __restrict__ in, unsigned short* __restrict__ out) {
  size_t i = (size_t)(blockIdx.x * 256 + threadIdx.x) * 8;
  float4 a = *reinterpret_cast<const float4*>(in + i);
  float4 b = *reinterpret_cast<const float4*>(in + i + 4);
  s16x8 h;
  h[0] = (short)f2bf(a.x); h[1] = (short)f2bf(a.y); h[2] = (short)f2bf(a.z); h[3] = (short)f2bf(a.w);
  h[4] = (short)f2bf(b.x); h[5] = (short)f2bf(b.y); h[6] = (short)f2bf(b.z); h[7] = (short)f2bf(b.w);
  *reinterpret_cast<s16x8*>(out + i) = h;
}

// ---------- softmax (sums 16 partials) + applied partial ----------
__global__ __launch_bounds__(256)
void softmax_applied(const float* __restrict__ part_sc, const int* __restrict__ pad,
                     const float* __restrict__ ch, float* __restrict__ part) {
  const int g = blockIdx.x, b = blockIdx.y, t = threadIdx.x;
  const int lane = t & 63, w = t >> 6;
  __shared__ float at[256];
  __shared__ float red[8];
  float sv = 0.f, v = -3.4e38f;
  if (t < Cctx) {
    float s8 = 0.f;
    #pragma unroll
    for (int mx = 0; mx < 16; ++mx) s8 += part_sc[mx * 12800 + b * Cctx + t];
    sv = pad[b * Cctx + t] ? NEG_INF_V : s8;
    v = sv;
  }
  #pragma unroll
  for (int o = 1; o < 64; o <<= 1) v = fmaxf(v, __shfl_xor(v, o));
  if (lane == 0) red[w] = v;
  __syncthreads();
  float m = fmaxf(fmaxf(red[0], red[1]), fmaxf(red[2], red[3]));
  float e = (t < Cctx) ? expf(sv - m) : 0.f;
  float s = e;
  #pragma unroll
  for (int o = 1; o < 64; o <<= 1) s += __shfl_xor(s, o);
  if (lane == 0) red[4 + w] = s;
  __syncthreads();
  float tot = red[4] + red[5] + red[6] + red[7];
  at[t] = e / tot;
  __syncthreads();
  const int h = t * 4;
  float4 a4 = make_float4(0.f, 0.f, 0.f, 0.f);
  for (int c2 = g * 25; c2 < g * 25 + 25; ++c2) {
    float a = at[c2];
    float4 vv = *reinterpret_cast<const float4*>(&ch[((size_t)b * Cctx + c2) * Hdim + h]);
    a4.x += a * vv.x; a4.y += a * vv.y; a4.z += a * vv.z; a4.w += a * vv.w;
  }
  *reinterpret_cast<float4*>(&part[((size_t)b * 8 + g) * Hdim + h]) = a4;
}

__global__ void build_xb(const float* __restrict__ inp, const float* __restrict__ topic,
                         const float* __restrict__ part, unsigned short* __restrict__ xb) {
  int j = blockIdx.x * 256 + threadIdx.x;
  int b = blockIdx.y;
  float v;
  if (j < 1024) v = inp[b * 1024 + j];
  else if (j < 2048) v = topic[b * 1024 + (j - 1024)];
  else {
    const float* pp = &part[(size_t)b * 8 * Hdim + (j - 2048)];
    v = 0.f;
    #pragma unroll
    for (int g = 0; g < 8; ++g) v += pp[g * Hdim];
  }
  xb[(size_t)b * 3072 + j] = f2bf(v);
}

__global__ void gru_gate(const float* __restrict__ pgi, const float* __restrict__ bih,
                         const float* __restrict__ gh, const float* __restrict__ h0,
                         float* __restrict__ out_h, unsigned short* __restrict__ hnb) {
  int idx = blockIdx.x * 256 + threadIdx.x;
  int b = idx >> 10, j = idx & 1023;
  float gr = bih[j], gz = bih[1024 + j], gn = bih[2048 + j];
  const float* pb = pgi + (size_t)b * 3072;
  #pragma unroll
  for (int w = 0; w < 4; ++w) {
    const float* pw = pb + (size_t)w * 64 * 3072;
    gr += pw[j]; gz += pw[1024 + j]; gn += pw[2048 + j];
  }
  const float* ghb = gh + (size_t)b * 3072;
  float r = 1.f / (1.f + expf(-(gr + ghb[j])));
  float z = 1.f / (1.f + expf(-(gz + ghb[1024 + j])));
  float n = tanhf(gn + r * ghb[2048 + j]);
  float h = (1.f - z) * n + z * h0[idx];
  out_h[idx] = h;
  hnb[idx] = f2bf(h);
}

// ---------- fused log-softmax ----------
__global__ __launch_bounds__(1024)
void lse_fused(float* __restrict__ out) {
  const int b = blockIdx.x, t = threadIdx.x, lane = t & 63, w = t >> 6;
  __shared__ float red[16];
  float* row = out + (size_t)b * Vv;
  float m = -3.4e38f;
  for (int i = t; i < Vv; i += 1024) m = fmaxf(m, row[i]);
  #pragma unroll
  for (int o = 1; o < 64; o <<= 1) m = fmaxf(m, __shfl_xor(m, o));
  if (lane == 0) red[w] = m;
  __syncthreads();
  float mm = red[0];
  #pragma unroll
  for (int k = 1; k < 16; ++k) mm = fmaxf(mm, red[k]);
  float s = 0.f;
  for (int i = t; i < Vv; i += 1024) s += expf(row[i] - mm);
  #pragma unroll
  for (int o = 1; o < 64; o <<= 1) s += __shfl_xor(s, o);
  __syncthreads();
  if (lane == 0) red[w] = s;
  __syncthreads();
  float ss = 0.f;
  #pragma unroll
  for (int k = 0; k < 16; ++k) ss += red[k];
  float lse = mm + logf(ss);
  for (int i = t; i < Vv; i += 1024) row[i] -= lse;
}

extern "C" void kernel_launch(void* const* d_in, const int* in_sizes, int n_in,
                              void* d_out, int out_size, void* d_ws, size_t ws_size,
                              hipStream_t stream) {
  const float* input  = (const float*)d_in[0];
  const float* hidden = (const float*)d_in[1];
  const float* lch    = (const float*)d_in[2];
  const float* ch     = (const float*)d_in[3];
  const float* topic  = (const float*)d_in[4];
  const int*   pad    = (const int*)d_in[5];
  const float* dyna_W = (const float*)d_in[6];
  const float* dyna_U = (const float*)d_in[7];
  const float* dyna_v = (const float*)d_in[8];
  const float* W_ih   = (const float*)d_in[9];
  const float* W_hh   = (const float*)d_in[10];
  const float* b_ih   = (const float*)d_in[11];
  const float* b_hh   = (const float*)d_in[12];
  const float* W_out  = (const float*)d_in[13];
  const float* b_out  = (const float*)d_in[14];

  float* out   = (float*)d_out;
  float* out_h = out + (size_t)Bsz * Vv;

  float* p = (float*)d_ws;
  float* Wt      = p; p += 1024 * 1024;
  float* q       = p; p += Bsz * Hdim;
  float* part_sc = p; p += 16 * Bsz * Cctx;
  float* part_ap = p; p += Bsz * 8 * Hdim;
  float* gh      = p; p += Bsz * 3072;
  float* part_gi = p; p += 4 * Bsz * 3072;
  unsigned short* up = (unsigned short*)p;
  unsigned short* ub  = up; up += 1024 * 1024;
  unsigned short* lb  = up; up += (size_t)Cctx * Bsz * Hdim;
  unsigned short* h0b = up; up += Bsz * Hdim;
  unsigned short* hnb = up; up += Bsz * Hdim;
  unsigned short* xb  = up; up += Bsz * 3072;

  prep<<<dim3(32, 32, 3), 256, 0, stream>>>(dyna_W, dyna_U, hidden, Wt, ub, h0b);
  conv_bf16<<<(Cctx * Bsz * Hdim) / 2048, 256, 0, stream>>>(lch, lb);

  qgh_gemm<<<256, 64, 0, stream>>>(h0b, Wt, W_hh, b_hh, q, gh);

  // part_sc[slot][b][c], slot = mx*2 + wn-half (16 slots)
  gemm_att<<<dim3(8, 104), 512, 0, stream>>>(lb, ub, q, dyna_v, part_sc);

  softmax_applied<<<dim3(8, Bsz), 256, 0, stream>>>(part_sc, pad, ch, part_ap);
  build_xb<<<dim3(12, Bsz), 256, 0, stream>>>(input, topic, part_ap, xb);

  gi_split<<<dim3(192, 4), 64, 0, stream>>>(xb, W_ih, part_gi);

  gru_gate<<<(Bsz * Hdim) / 256, 256, 0, stream>>>(part_gi, b_ih, gh, hidden, out_h, hnb);

  stream_gemm<2><<<(Vv + 15) / 16, 64, 0, stream>>>(hnb, W_out, Vv, Hdim, b_out, out);

  lse_fused<<<Bsz, 1024, 0, stream>>>(out);
}

// Round 15
// 221.472 us; speedup vs baseline: 1.0290x; 1.0290x over previous
//
#include <hip/hip_runtime.h>
#include <hip/hip_bf16.h>
#include <math.h>

constexpr int Bsz = 64, Cctx = 200, Hdim = 1024, Vv = 50257;
constexpr int NBLK = (Vv + 15) / 16;   // 3142 logits col-blocks
constexpr float NEG_INF_V = -100000.0f;

typedef __attribute__((ext_vector_type(8))) short s16x8;
typedef __attribute__((ext_vector_type(4))) float fx4;
typedef unsigned int u32;

__device__ __forceinline__ unsigned short f2bf(float f) {
  unsigned int u = __builtin_bit_cast(unsigned int, f);
  unsigned int r = (u + 0x7fffu + ((u >> 16) & 1u)) >> 16;
  return (unsigned short)r;
}

__device__ __forceinline__ float fast_tanh(float x) {
  float e2 = __expf(2.f * x);
  return 1.f - 2.f / (e2 + 1.f);
}

__device__ __forceinline__ void gl_lds16(const unsigned short* g, unsigned short* l) {
  __builtin_amdgcn_global_load_lds(
      (const __attribute__((address_space(1))) u32*)g,
      (__attribute__((address_space(3))) u32*)l, 16, 0, 0);
}

// ---------- attention GEMM: round-13 proven config (128x64, 1600 blocks, 24KB LDS) ----------
__global__ __launch_bounds__(256)
void gemm_att(const unsigned short* __restrict__ Ab, const unsigned short* __restrict__ Bb,
              const float* __restrict__ qmat, const float* __restrict__ vvec,
              float* __restrict__ part_sc) {
  __shared__ unsigned short As[128 * 64];   // 16 KB
  __shared__ unsigned short Bs[64 * 64];    //  8 KB
  const int bx = blockIdx.x, by = blockIdx.y;   // grid (8, 208)
  const int xcd = bx;
  const int my = xcd + 8 * (by >> 4);
  const int mx = by & 15;
  if (my >= 100) return;
  const int bm0 = my * 128, bn0 = mx * 64;
  const int tid = threadIdx.x, lane = tid & 63, wid = tid >> 6;
  const int wm0 = wid * 32;
  const int ar = lane & 15, q4 = lane >> 4;
  const int sw = ar & 7;

  fx4 acc[2][4] = {};

  for (int t = 0; t < 16; ++t) {
    const int kt = t * 64;
    #pragma unroll
    for (int i = 0; i < 4; ++i) {
      int s = tid + i * 256;
      int row = s >> 3;
      int sc = ((s & 7) ^ (row & 7)) * 8;
      gl_lds16(&Ab[(size_t)(bm0 + row) * Hdim + kt + sc], &As[s * 8]);
    }
    #pragma unroll
    for (int i = 0; i < 2; ++i) {
      int s = tid + i * 256;
      int row = s >> 3;
      int sc = ((s & 7) ^ (row & 7)) * 8;
      gl_lds16(&Bb[(size_t)(bn0 + row) * Hdim + kt + sc], &Bs[s * 8]);
    }
    __syncthreads();
    #pragma unroll
    for (int kk = 0; kk < 2; ++kk) {
      s16x8 a[2], b[4];
      #pragma unroll
      for (int i = 0; i < 2; ++i)
        a[i] = *reinterpret_cast<const s16x8*>(
            &As[(wm0 + i * 16 + ar) * 64 + (((kk * 4 + q4) ^ sw) * 8)]);
      #pragma unroll
      for (int j2 = 0; j2 < 4; ++j2)
        b[j2] = *reinterpret_cast<const s16x8*>(
            &Bs[(j2 * 16 + ar) * 64 + (((kk * 4 + q4) ^ sw) * 8)]);
      #pragma unroll
      for (int i = 0; i < 2; ++i)
        #pragma unroll
        for (int j2 = 0; j2 < 4; ++j2)
          acc[i][j2] = __builtin_amdgcn_mfma_f32_16x16x32_bf16(a[i], b[j2], acc[i][j2], 0, 0, 0);
    }
    __syncthreads();
  }

  const int rg = q4 * 4, cg = ar;
  #pragma unroll
  for (int i = 0; i < 2; ++i) {
    #pragma unroll
    for (int p = 0; p < 4; ++p) {
      int mg = bm0 + wm0 + i * 16 + rg + p;
      int brow = mg & 63;
      float rs = 0.f;
      #pragma unroll
      for (int j2 = 0; j2 < 4; ++j2) {
        int ng = bn0 + j2 * 16 + cg;
        float t = fast_tanh(acc[i][j2][p] + qmat[brow * Hdim + ng]);
        rs += t * vvec[ng];
      }
      rs += __shfl_xor(rs, 1); rs += __shfl_xor(rs, 2);
      rs += __shfl_xor(rs, 4); rs += __shfl_xor(rs, 8);
      if (cg == 0) part_sc[mx * 12800 + brow * Cctx + (mg >> 6)] = rs;
    }
  }
}

// ---------- 1-wave streaming GEMM body, depth-1 prefetch ----------
__device__ __forceinline__ void stream_body(const unsigned short* ap, const float* bp,
                                            int stride, int extent, fx4 acc[4]) {
  float4 b0 = *reinterpret_cast<const float4*>(bp);
  float4 b1 = *reinterpret_cast<const float4*>(bp + 4);
  float4 b2 = *reinterpret_cast<const float4*>(bp + 32);
  float4 b3 = *reinterpret_cast<const float4*>(bp + 36);
  for (int kt = 0; kt < extent; kt += 64) {
    float4 c0 = b0, c1 = b1, c2 = b2, c3 = b3;
    if (kt + 64 < extent) {
      b0 = *reinterpret_cast<const float4*>(bp + kt + 64);
      b1 = *reinterpret_cast<const float4*>(bp + kt + 68);
      b2 = *reinterpret_cast<const float4*>(bp + kt + 96);
      b3 = *reinterpret_cast<const float4*>(bp + kt + 100);
    }
    s16x8 bf0, bf1;
    bf0[0] = (short)f2bf(c0.x); bf0[1] = (short)f2bf(c0.y);
    bf0[2] = (short)f2bf(c0.z); bf0[3] = (short)f2bf(c0.w);
    bf0[4] = (short)f2bf(c1.x); bf0[5] = (short)f2bf(c1.y);
    bf0[6] = (short)f2bf(c1.z); bf0[7] = (short)f2bf(c1.w);
    bf1[0] = (short)f2bf(c2.x); bf1[1] = (short)f2bf(c2.y);
    bf1[2] = (short)f2bf(c2.z); bf1[3] = (short)f2bf(c2.w);
    bf1[4] = (short)f2bf(c3.x); bf1[5] = (short)f2bf(c3.y);
    bf1[6] = (short)f2bf(c3.z); bf1[7] = (short)f2bf(c3.w);
    #pragma unroll
    for (int i = 0; i < 4; ++i) {
      s16x8 af = *reinterpret_cast<const s16x8*>(ap + (size_t)i * 16 * stride + kt);
      acc[i] = __builtin_amdgcn_mfma_f32_16x16x32_bf16(af, bf0, acc[i], 0, 0, 0);
    }
    #pragma unroll
    for (int i = 0; i < 4; ++i) {
      s16x8 af = *reinterpret_cast<const s16x8*>(ap + (size_t)i * 16 * stride + kt + 32);
      acc[i] = __builtin_amdgcn_mfma_f32_16x16x32_bf16(af, bf1, acc[i], 0, 0, 0);
    }
  }
}

// logits GEMM + bias + per-block log-softmax partials (m_loc, sumexp_loc)
__global__ __launch_bounds__(64)
void logits_gemm(const unsigned short* __restrict__ Ab, const float* __restrict__ Bm,
                 const float* __restrict__ bias, float* __restrict__ Cout,
                 float* __restrict__ pm, float* __restrict__ ps) {
  const int lane = threadIdx.x;
  const int n0 = blockIdx.x * 16;
  const int c = lane & 15, qq = lane >> 4;
  const int brow = min(n0 + c, Vv - 1);
  fx4 acc[4] = {};
  stream_body(Ab + (size_t)c * Hdim + qq * 8, Bm + (size_t)brow * Hdim + qq * 8,
              Hdim, Hdim, acc);
  const int n = n0 + c;
  const bool valid = n < Vv;
  float bv = valid ? bias[n] : 0.f;
  #pragma unroll
  for (int i = 0; i < 4; ++i) {
    #pragma unroll
    for (int p = 0; p < 4; ++p) {
      int row = i * 16 + qq * 4 + p;
      float val = acc[i][p] + bv;
      if (valid) Cout[(size_t)row * Vv + n] = val;
      // row-wise partials over this block's 16 cols (lanes sharing qq)
      float mv = valid ? val : -3.4e38f;
      mv = fmaxf(mv, __shfl_xor(mv, 1)); mv = fmaxf(mv, __shfl_xor(mv, 2));
      mv = fmaxf(mv, __shfl_xor(mv, 4)); mv = fmaxf(mv, __shfl_xor(mv, 8));
      float e = valid ? expf(val - mv) : 0.f;
      e += __shfl_xor(e, 1); e += __shfl_xor(e, 2);
      e += __shfl_xor(e, 4); e += __shfl_xor(e, 8);
      if (c == 0) {
        pm[(size_t)row * NBLK + blockIdx.x] = mv;
        ps[(size_t)row * NBLK + blockIdx.x] = e;
      }
    }
  }
}

// combine NBLK partials per row -> lse[b]
__global__ __launch_bounds__(256)
void lse_combine(const float* __restrict__ pm, const float* __restrict__ ps,
                 float* __restrict__ lse) {
  const int b = blockIdx.x, t = threadIdx.x, lane = t & 63, w = t >> 6;
  __shared__ float red[8];
  const float* pmb = pm + (size_t)b * NBLK;
  const float* psb = ps + (size_t)b * NBLK;
  float m = -3.4e38f;
  for (int i = t; i < NBLK; i += 256) m = fmaxf(m, pmb[i]);
  #pragma unroll
  for (int o = 1; o < 64; o <<= 1) m = fmaxf(m, __shfl_xor(m, o));
  if (lane == 0) red[w] = m;
  __syncthreads();
  float M = fmaxf(fmaxf(red[0], red[1]), fmaxf(red[2], red[3]));
  float s = 0.f;
  for (int i = t; i < NBLK; i += 256) s += psb[i] * expf(pmb[i] - M);
  #pragma unroll
  for (int o = 1; o < 64; o <<= 1) s += __shfl_xor(s, o);
  if (lane == 0) red[4 + w] = s;
  __syncthreads();
  if (t == 0) lse[b] = M + logf(red[4] + red[5] + red[6] + red[7]);
}

__global__ __launch_bounds__(256)
void lse_sub(float* __restrict__ out, const float* __restrict__ lse) {
  const int b = blockIdx.y;
  int i = blockIdx.x * 256 + threadIdx.x;
  if (i < Vv) out[(size_t)b * Vv + i] -= lse[b];
}

__global__ __launch_bounds__(64)
void qgh_gemm(const unsigned short* __restrict__ h0b, const float* __restrict__ Wt,
              const float* __restrict__ Whh, const float* __restrict__ bhh,
              float* __restrict__ q, float* __restrict__ gh) {
  const int lane = threadIdx.x;
  const int gw = blockIdx.x;
  const bool isq = gw < 64;
  const int n0 = isq ? gw * 16 : (gw - 64) * 16;
  const int N = isq ? 1024 : 3072;
  const float* B = isq ? Wt : Whh;
  const int c = lane & 15, qq = lane >> 4;
  fx4 acc[4] = {};
  stream_body(h0b + (size_t)c * 1024 + qq * 8, B + (size_t)(n0 + c) * 1024 + qq * 8,
              1024, 1024, acc);
  const int n = n0 + c;
  float bv = isq ? 0.f : bhh[n];
  float* C = isq ? q : gh;
  #pragma unroll
  for (int i = 0; i < 4; ++i)
    #pragma unroll
    for (int p = 0; p < 4; ++p)
      C[(size_t)(i * 16 + qq * 4 + p) * N + n] = acc[i][p] + bv;
}

__global__ __launch_bounds__(64)
void gi_split(const unsigned short* __restrict__ xb, const float* __restrict__ Wih,
              float* __restrict__ part) {
  const int lane = threadIdx.x;
  const int t = blockIdx.x;
  const int w = blockIdx.y;
  const int c = lane & 15, qq = lane >> 4;
  constexpr int K = 3072, CH = 768;
  fx4 acc[4] = {};
  stream_body(xb + (size_t)c * K + w * CH + qq * 8,
              Wih + (size_t)(t * 16 + c) * K + w * CH + qq * 8, K, CH, acc);
  float* po = part + (size_t)w * 64 * 3072;
  const int n = t * 16 + c;
  #pragma unroll
  for (int i = 0; i < 4; ++i)
    #pragma unroll
    for (int p = 0; p < 4; ++p)
      po[(size_t)(i * 16 + qq * 4 + p) * 3072 + n] = acc[i][p];
}

// ---------- prep_all: W transpose + U transpose(bf16) + h0 conv + lch conv, one grid ----------
__global__ __launch_bounds__(256)
void prep_all(const float* __restrict__ dW, const float* __restrict__ dU,
              const float* __restrict__ h0, const float* __restrict__ lch,
              float* __restrict__ Wt, unsigned short* __restrict__ ub,
              unsigned short* __restrict__ h0b, unsigned short* __restrict__ lb) {
  const int bid = blockIdx.x;
  const int tid = threadIdx.x;
  if (bid < 2048) {
    __shared__ float t[32][33];
    const int zb = bid >> 10;
    const int t2 = bid & 1023;
    const int bx = (t2 & 31) * 32, by = (t2 >> 5) * 32;
    const int tx = tid & 31, ty = tid >> 5;
    const float* in = zb ? dU : dW;
    #pragma unroll
    for (int r = 0; r < 32; r += 8) t[ty + r][tx] = in[(size_t)(by + ty + r) * 1024 + bx + tx];
    __syncthreads();
    if (zb == 0) {
      #pragma unroll
      for (int r = 0; r < 32; r += 8) Wt[(size_t)(bx + ty + r) * 1024 + by + tx] = t[tx][ty + r];
    } else {
      #pragma unroll
      for (int r = 0; r < 32; r += 8) ub[(size_t)(bx + ty + r) * 1024 + by + tx] = f2bf(t[tx][ty + r]);
    }
  } else if (bid < 2080) {
    size_t i = (size_t)((bid - 2048) * 256 + tid) * 8;   // 64*1024 elems
    float4 a = *reinterpret_cast<const float4*>(h0 + i);
    float4 b = *reinterpret_cast<const float4*>(h0 + i + 4);
    s16x8 h;
    h[0] = (short)f2bf(a.x); h[1] = (short)f2bf(a.y); h[2] = (short)f2bf(a.z); h[3] = (short)f2bf(a.w);
    h[4] = (short)f2bf(b.x); h[5] = (short)f2bf(b.y); h[6] = (short)f2bf(b.z); h[7] = (short)f2bf(b.w);
    *reinterpret_cast<s16x8*>(h0b + i) = h;
  } else {
    size_t i = (size_t)((bid - 2080) * 256 + tid) * 8;   // 200*64*1024 elems
    float4 a = *reinterpret_cast<const float4*>(lch + i);
    float4 b = *reinterpret_cast<const float4*>(lch + i + 4);
    s16x8 h;
    h[0] = (short)f2bf(a.x); h[1] = (short)f2bf(a.y); h[2] = (short)f2bf(a.z); h[3] = (short)f2bf(a.w);
    h[4] = (short)f2bf(b.x); h[5] = (short)f2bf(b.y); h[6] = (short)f2bf(b.z); h[7] = (short)f2bf(b.w);
    *reinterpret_cast<s16x8*>(lb + i) = h;
  }
}

// ---------- softmax (sums 16 partials) + applied partial ----------
__global__ __launch_bounds__(256)
void softmax_applied(const float* __restrict__ part_sc, const int* __restrict__ pad,
                     const float* __restrict__ ch, float* __restrict__ part) {
  const int g = blockIdx.x, b = blockIdx.y, t = threadIdx.x;
  const int lane = t & 63, w = t >> 6;
  __shared__ float at[256];
  __shared__ float red[8];
  float sv = 0.f, v = -3.4e38f;
  if (t < Cctx) {
    float s8 = 0.f;
    #pragma unroll
    for (int mx = 0; mx < 16; ++mx) s8 += part_sc[mx * 12800 + b * Cctx + t];
    sv = pad[b * Cctx + t] ? NEG_INF_V : s8;
    v = sv;
  }
  #pragma unroll
  for (int o = 1; o < 64; o <<= 1) v = fmaxf(v, __shfl_xor(v, o));
  if (lane == 0) red[w] = v;
  __syncthreads();
  float m = fmaxf(fmaxf(red[0], red[1]), fmaxf(red[2], red[3]));
  float e = (t < Cctx) ? expf(sv - m) : 0.f;
  float s = e;
  #pragma unroll
  for (int o = 1; o < 64; o <<= 1) s += __shfl_xor(s, o);
  if (lane == 0) red[4 + w] = s;
  __syncthreads();
  float tot = red[4] + red[5] + red[6] + red[7];
  at[t] = e / tot;
  __syncthreads();
  const int h = t * 4;
  float4 a4 = make_float4(0.f, 0.f, 0.f, 0.f);
  for (int c2 = g * 25; c2 < g * 25 + 25; ++c2) {
    float a = at[c2];
    float4 vv = *reinterpret_cast<const float4*>(&ch[((size_t)b * Cctx + c2) * Hdim + h]);
    a4.x += a * vv.x; a4.y += a * vv.y; a4.z += a * vv.z; a4.w += a * vv.w;
  }
  *reinterpret_cast<float4*>(&part[((size_t)b * 8 + g) * Hdim + h]) = a4;
}

__global__ void build_xb(const float* __restrict__ inp, const float* __restrict__ topic,
                         const float* __restrict__ part, unsigned short* __restrict__ xb) {
  int j = blockIdx.x * 256 + threadIdx.x;
  int b = blockIdx.y;
  float v;
  if (j < 1024) v = inp[b * 1024 + j];
  else if (j < 2048) v = topic[b * 1024 + (j - 1024)];
  else {
    const float* pp = &part[(size_t)b * 8 * Hdim + (j - 2048)];
    v = 0.f;
    #pragma unroll
    for (int g = 0; g < 8; ++g) v += pp[g * Hdim];
  }
  xb[(size_t)b * 3072 + j] = f2bf(v);
}

__global__ void gru_gate(const float* __restrict__ pgi, const float* __restrict__ bih,
                         const float* __restrict__ gh, const float* __restrict__ h0,
                         float* __restrict__ out_h, unsigned short* __restrict__ hnb) {
  int idx = blockIdx.x * 256 + threadIdx.x;
  int b = idx >> 10, j = idx & 1023;
  float gr = bih[j], gz = bih[1024 + j], gn = bih[2048 + j];
  const float* pb = pgi + (size_t)b * 3072;
  #pragma unroll
  for (int w = 0; w < 4; ++w) {
    const float* pw = pb + (size_t)w * 64 * 3072;
    gr += pw[j]; gz += pw[1024 + j]; gn += pw[2048 + j];
  }
  const float* ghb = gh + (size_t)b * 3072;
  float r = 1.f / (1.f + expf(-(gr + ghb[j])));
  float z = 1.f / (1.f + expf(-(gz + ghb[1024 + j])));
  float n = tanhf(gn + r * ghb[2048 + j]);
  float h = (1.f - z) * n + z * h0[idx];
  out_h[idx] = h;
  hnb[idx] = f2bf(h);
}

extern "C" void kernel_launch(void* const* d_in, const int* in_sizes, int n_in,
                              void* d_out, int out_size, void* d_ws, size_t ws_size,
                              hipStream_t stream) {
  const float* input  = (const float*)d_in[0];
  const float* hidden = (const float*)d_in[1];
  const float* lch    = (const float*)d_in[2];
  const float* ch     = (const float*)d_in[3];
  const float* topic  = (const float*)d_in[4];
  const int*   pad    = (const int*)d_in[5];
  const float* dyna_W = (const float*)d_in[6];
  const float* dyna_U = (const float*)d_in[7];
  const float* dyna_v = (const float*)d_in[8];
  const float* W_ih   = (const float*)d_in[9];
  const float* W_hh   = (const float*)d_in[10];
  const float* b_ih   = (const float*)d_in[11];
  const float* b_hh   = (const float*)d_in[12];
  const float* W_out  = (const float*)d_in[13];
  const float* b_out  = (const float*)d_in[14];

  float* out   = (float*)d_out;
  float* out_h = out + (size_t)Bsz * Vv;

  float* p = (float*)d_ws;
  float* Wt      = p; p += 1024 * 1024;
  float* q       = p; p += Bsz * Hdim;
  float* part_sc = p; p += 16 * Bsz * Cctx;
  float* part_ap = p; p += Bsz * 8 * Hdim;
  float* gh      = p; p += Bsz * 3072;
  float* part_gi = p; p += 4 * Bsz * 3072;
  float* pm      = p; p += (size_t)Bsz * NBLK;
  float* ps      = p; p += (size_t)Bsz * NBLK;
  float* lse     = p; p += Bsz;
  unsigned short* up = (unsigned short*)p;
  unsigned short* ub  = up; up += 1024 * 1024;
  unsigned short* lb  = up; up += (size_t)Cctx * Bsz * Hdim;
  unsigned short* h0b = up; up += Bsz * Hdim;
  unsigned short* hnb = up; up += Bsz * Hdim;
  unsigned short* xb  = up; up += Bsz * 3072;

  // transposes + bf16 conversions in one concurrent grid
  prep_all<<<8480, 256, 0, stream>>>(dyna_W, dyna_U, hidden, lch, Wt, ub, h0b, lb);

  qgh_gemm<<<256, 64, 0, stream>>>(h0b, Wt, W_hh, b_hh, q, gh);

  // part_sc[mx][b][c] = partial tanh(q + lch@U).v over 64-col panel mx
  gemm_att<<<dim3(8, 208), 256, 0, stream>>>(lb, ub, q, dyna_v, part_sc);

  softmax_applied<<<dim3(8, Bsz), 256, 0, stream>>>(part_sc, pad, ch, part_ap);
  build_xb<<<dim3(12, Bsz), 256, 0, stream>>>(input, topic, part_ap, xb);

  gi_split<<<dim3(192, 4), 64, 0, stream>>>(xb, W_ih, part_gi);

  gru_gate<<<(Bsz * Hdim) / 256, 256, 0, stream>>>(part_gi, b_ih, gh, hidden, out_h, hnb);

  // logits + bias + per-block lse partials
  logits_gemm<<<NBLK, 64, 0, stream>>>(hnb, W_out, b_out, out, pm, ps);

  lse_combine<<<Bsz, 256, 0, stream>>>(pm, ps, lse);
  lse_sub<<<dim3((Vv + 255) / 256, Bsz), 256, 0, stream>>>(out, lse);
}